// Round 4
// baseline (308.302 us; speedup 1.0000x reference)
//
#include <hip/hip_runtime.h>
#include <utility>

typedef float v2f __attribute__((ext_vector_type(2)));

#define HDT 0.05f      // dt/2
#define KSTEPS 5       // Horner order: rel err ~rho^6, rho<=0.33 worst -> << bf16 ULP

// per-system LDS layout (float4 slots): logical quad qd in [-10, 522);
// idx = qd + 10 in [0, 532); phys slot = idx + idx/8 (pad 1 per 8) -> max 597.
#define SYS_SLOTS 600   // 9.6 KB/system, 38.4 KB/block (4 systems)

__device__ __forceinline__ float bf2f(unsigned int u) {
    return __uint_as_float(u << 16);
}
__device__ __forceinline__ unsigned int f2bf(float x) {
    unsigned int b = __float_as_uint(x);
    return (b + 0x7FFFu + ((b >> 16) & 1u)) >> 16;   // RNE
}
__device__ __forceinline__ float rfl(float x) {
    return __int_as_float(__builtin_amdgcn_readfirstlane(__float_as_int(x)));
}

// compile-time for
template <int... Is, class F>
__device__ __forceinline__ void static_for_impl(std::integer_sequence<int, Is...>, F&& f) {
    (f(std::integral_constant<int, Is>{}), ...);
}
template <int N, class F>
__device__ __forceinline__ void static_for(F&& f) {
    static_for_impl(std::make_integer_sequence<int, N>{}, (F&&)f);
}

// stencil coefficient slot for signed distance d (compile-time)
__host__ __device__ constexpr int cidx(int d) {
    int a = d < 0 ? -d : d;
    return (a==0)?0:(a==1)?1:(a==2)?2:(a==3)?3:(a==4)?4:(a==5)?5:(a==6)?6:
           (a==8)?7:(a==10)?8:(a==12)?9:(a==16)?10:(a==20)?11:-1;
}

// ---- dtype probe: one uint4/lane = 256 sampled words, one memory round trip ----
__global__ void detect_dtype(const uint4* __restrict__ w, int* __restrict__ flag) {
    uint4 v = w[threadIdx.x];
    int cnt = 0;
    unsigned int ws[4] = {v.x, v.y, v.z, v.w};
    #pragma unroll
    for (int i = 0; i < 4; ++i) {
        unsigned int e = (ws[i] >> 7) & 0xFFu;     // exponent field of low-half bf16
        cnt += (e >= 0x78u && e <= 0x82u) ? 1 : 0; // |x| in [2^-7, 8]
    }
    #pragma unroll
    for (int off = 32; off; off >>= 1) cnt += __shfl_xor(cnt, off, 64);
    if (threadIdx.x == 0) *flag = (cnt > 128) ? 1 : 0;
}

__global__ __launch_bounds__(256, 2)
void cayley_main(const void* __restrict__ psi_r, const void* __restrict__ psi_i,
                 const void* __restrict__ alpha, const void* __restrict__ ham_w,
                 void* __restrict__ out, const int* __restrict__ flagp)
{
    __shared__ float4 lds4[4 * SYS_SLOTS];     // 38400 B

    const int lane = threadIdx.x & 63;
    const int wv   = threadIdx.x >> 6;
    const int sys  = (blockIdx.x << 2) + wv;   // [0, 16384)
    float4* const sl   = lds4 + wv * SYS_SLOTS;
    // single base for ALL reads and writes; every offset is a compile-time imm.
    // reads:  window quad c in [0,28): slot = 9L + c + c/8        (qd = 8L+c-10)
    // writes: own quad k in [0,8):     slot = 9L + 11+k (+1 if k>5)
    float4* const base = sl + 9 * lane;

    const bool isbf = (*flagp) != 0;

    // ---- combined stencil coefficients (h-scaled), wave-uniform -> SGPR ----
    float hw[15];
    if (isbf) {
        const unsigned short* p = (const unsigned short*)ham_w;
        #pragma unroll
        for (int i = 0; i < 15; ++i) hw[i] = bf2f((unsigned int)p[i]);
    } else {
        const float* p = (const float*)ham_w;
        #pragma unroll
        for (int i = 0; i < 15; ++i) hw[i] = p[i];
    }
    float cs[12];
    {
        float s = 0.f;
        #pragma unroll
        for (int i = 0; i < 15; ++i) s += hw[i];
        cs[0]  = rfl( 2.f*HDT*s);                       // center
        cs[1]  = rfl(-HDT* hw[0]);                      // off 1
        cs[2]  = rfl(-HDT*(hw[1]+hw[5]));               // off 2
        cs[3]  = rfl(-HDT* hw[2]);                      // off 3
        cs[4]  = rfl(-HDT*(hw[3]+hw[6]+hw[10]));        // off 4
        cs[5]  = rfl(-HDT* hw[4]);                      // off 5
        cs[6]  = rfl(-HDT* hw[7]);                      // off 6
        cs[7]  = rfl(-HDT*(hw[8]+hw[11]));              // off 8
        cs[8]  = rfl(-HDT* hw[9]);                      // off 10
        cs[9]  = rfl(-HDT* hw[12]);                     // off 12
        cs[10] = rfl(-HDT* hw[13]);                     // off 16
        cs[11] = rfl(-HDT* hw[14]);                     // off 20
    }

    // halo duplication (circular wrap): quads 0..9 also at idx 522+qd,
    // quads 502..511 also at idx qd-502. Only lanes 0,1,62,63 participate.
    int hoff[8];
    #pragma unroll
    for (int k = 0; k < 8; ++k) {
        int qd = 8*lane + k;
        int h = -1;
        if (qd < 10)  { int idx = qd + 522; h = idx + (idx >> 3); }
        if (qd >= 502){ int idx = qd - 502; h = idx + (idx >> 3); }
        hoff[k] = h;
    }

    // ---- load psi (16 points per lane) and alpha ----
    float pr[16], pq[16], al[16];
    if (isbf) {
        const unsigned short* bR = (const unsigned short*)psi_r + (size_t)sys*1024 + lane*16;
        const unsigned short* bI = (const unsigned short*)psi_i + (size_t)sys*1024 + lane*16;
        const unsigned short* bA = (const unsigned short*)alpha  + lane*16;
        static_for<2>([&](auto hI) {
            constexpr int h = hI.value;
            uint4 a = ((const uint4*)bR)[h];
            uint4 b = ((const uint4*)bI)[h];
            uint4 c = ((const uint4*)bA)[h];
            pr[h*8+0]=bf2f(a.x&0xFFFFu); pr[h*8+1]=bf2f(a.x>>16);
            pr[h*8+2]=bf2f(a.y&0xFFFFu); pr[h*8+3]=bf2f(a.y>>16);
            pr[h*8+4]=bf2f(a.z&0xFFFFu); pr[h*8+5]=bf2f(a.z>>16);
            pr[h*8+6]=bf2f(a.w&0xFFFFu); pr[h*8+7]=bf2f(a.w>>16);
            pq[h*8+0]=bf2f(b.x&0xFFFFu); pq[h*8+1]=bf2f(b.x>>16);
            pq[h*8+2]=bf2f(b.y&0xFFFFu); pq[h*8+3]=bf2f(b.y>>16);
            pq[h*8+4]=bf2f(b.z&0xFFFFu); pq[h*8+5]=bf2f(b.z>>16);
            pq[h*8+6]=bf2f(b.w&0xFFFFu); pq[h*8+7]=bf2f(b.w>>16);
            al[h*8+0]=bf2f(c.x&0xFFFFu); al[h*8+1]=bf2f(c.x>>16);
            al[h*8+2]=bf2f(c.y&0xFFFFu); al[h*8+3]=bf2f(c.y>>16);
            al[h*8+4]=bf2f(c.z&0xFFFFu); al[h*8+5]=bf2f(c.z>>16);
            al[h*8+6]=bf2f(c.w&0xFFFFu); al[h*8+7]=bf2f(c.w>>16);
        });
    } else {
        const float* fR = (const float*)psi_r + (size_t)sys*1024 + lane*16;
        const float* fI = (const float*)psi_i + (size_t)sys*1024 + lane*16;
        const float* fA = (const float*)alpha  + lane*16;
        static_for<4>([&](auto hI) {
            constexpr int h = hI.value;
            float4 a = ((const float4*)fR)[h];
            float4 b = ((const float4*)fI)[h];
            float4 c = ((const float4*)fA)[h];
            pr[4*h]=a.x; pr[4*h+1]=a.y; pr[4*h+2]=a.z; pr[4*h+3]=a.w;
            pq[4*h]=b.x; pq[4*h+1]=b.y; pq[4*h+2]=b.z; pq[4*h+3]=b.w;
            al[4*h]=c.x; al[4*h+1]=c.y; al[4*h+2]=c.z; al[4*h+3]=c.w;
        });
    }

    // ---- intensity mean (wave reduction; one wave == one system) ----
    float ssum = 0.f;
    #pragma unroll
    for (int k = 0; k < 16; ++k) ssum += pr[k]*pr[k] + pq[k]*pq[k];
    #pragma unroll
    for (int off = 32; off; off >>= 1) ssum += __shfl_xor(ssum, off, 64);
    const float inv = 1.f / (ssum * (1.f/1024.f) + 1e-8f);

    // ---- nonlinear phase rotation -> cur ----
    v2f cur[16];
    static_for<16>([&](auto kI) {
        constexpr int k = kI.value;
        float inten = (pr[k]*pr[k] + pq[k]*pq[k]) * inv;
        float ph = al[k] * inten;
        float cc = __cosf(ph), sn = __sinf(ph);
        cur[k].x = pr[k]*cc - pq[k]*sn;
        cur[k].y = pr[k]*sn + pq[k]*cc;
    });

    v2f acc[16], b[16], t[16];

    // LDS is wave-private (own region) -> no __syncthreads; per-wave lgkmcnt
    // ordering (compiler-inserted) is sufficient.
    auto ldswrite = [&](v2f (&arr)[16]) {
        static_for<8>([&](auto kI) {
            constexpr int k = kI.value;
            constexpr int woff = (k <= 5) ? (11 + k) : (12 + k);
            float4 val = make_float4(arr[2*k].x, arr[2*k].y,
                                     arr[2*k+1].x, arr[2*k+1].y);
            base[woff] = val;
            if (hoff[k] >= 0) sl[hoff[k]] = val;   // wrap halo (5 lanes active)
        });
    };
    // acc = (h*H) applied to LDS-resident complex vector (packed r,i)
    auto stencil = [&]() {
        static_for<16>([&](auto kI) { acc[kI.value].x = 0.f; acc[kI.value].y = 0.f; });
        static_for<28>([&](auto cI) {
            constexpr int c = cI.value;              // window quad
            constexpr int roff = c + (c >> 3);       // padded slot offset
            float4 q = base[roff];
            v2f e0; e0.x = q.x; e0.y = q.y;
            v2f e1; e1.x = q.z; e1.y = q.w;
            static_for<16>([&](auto kI) {
                constexpr int k = kI.value;
                // source point j = 2c+e covers d = 16L-20+j; tap dist = j-20-k
                constexpr int id0 = cidx(2*c     - 20 - k);
                constexpr int id1 = cidx(2*c + 1 - 20 - k);
                if constexpr (id0 >= 0) acc[k] += cs[id0] * e0;
                if constexpr (id1 >= 0) acc[k] += cs[id1] * e1;
            });
        });
    };

    ldswrite(cur);
    stencil();
    // rhs b = (I - i*h*H) rot : b_r = rot_r + hH(rot_i) ; b_i = rot_i - hH(rot_r)
    static_for<16>([&](auto kI) {
        constexpr int k = kI.value;
        b[k].x = cur[k].x + acc[k].y;
        b[k].y = cur[k].y - acc[k].x;
    });
    ldswrite(b);   // t0 = b

    // Horner: t <- b - i*h*H t  ==> t_r = b_r + hH(t_i), t_i = b_i - hH(t_r)
    #pragma unroll 1
    for (int itn = 0; itn < KSTEPS; ++itn) {
        stencil();
        static_for<16>([&](auto kI) {
            constexpr int k = kI.value;
            t[k].x = b[k].x + acc[k].y;
            t[k].y = b[k].y - acc[k].x;
        });
        if (itn != KSTEPS - 1) ldswrite(t);
    }

    // ---- store interleaved (r,i) pairs: 32 contiguous values at 32L ----
    if (isbf) {
        unsigned short* po = (unsigned short*)out + (size_t)sys*2048 + lane*32;
        uint4* po4 = (uint4*)po;
        static_for<4>([&](auto hI) {
            constexpr int h = hI.value;
            uint4 v;
            v.x = f2bf(t[4*h+0].x) | (f2bf(t[4*h+0].y) << 16);
            v.y = f2bf(t[4*h+1].x) | (f2bf(t[4*h+1].y) << 16);
            v.z = f2bf(t[4*h+2].x) | (f2bf(t[4*h+2].y) << 16);
            v.w = f2bf(t[4*h+3].x) | (f2bf(t[4*h+3].y) << 16);
            po4[h] = v;
        });
    } else {
        float* po = (float*)out + (size_t)sys*2048 + lane*32;
        static_for<8>([&](auto kI) {
            constexpr int k8 = kI.value;
            *(float4*)(po + 4*k8) = make_float4(t[2*k8].x, t[2*k8].y,
                                                t[2*k8+1].x, t[2*k8+1].y);
        });
    }
}

extern "C" void kernel_launch(void* const* d_in, const int* in_sizes, int n_in,
                              void* d_out, int out_size, void* d_ws, size_t ws_size,
                              hipStream_t stream)
{
    (void)in_sizes; (void)n_in; (void)out_size; (void)ws_size;
    detect_dtype<<<dim3(1), dim3(64), 0, stream>>>((const uint4*)d_in[0], (int*)d_ws);
    cayley_main<<<dim3(4096), dim3(256), 0, stream>>>(d_in[0], d_in[1], d_in[2], d_in[3],
                                                      d_out, (const int*)d_ws);
}